// Round 1
// baseline (678.628 us; speedup 1.0000x reference)
//
#include <hip/hip_runtime.h>

#define H_DIM 2048
#define DMID  1024
#define DOUT  256
#define NTOK  32768
#define NIMG  32

typedef __attribute__((ext_vector_type(8))) __bf16 bf16x8;
typedef __attribute__((ext_vector_type(4))) float f32x4;

__device__ __forceinline__ unsigned f2bf(float f) {
  unsigned u = __builtin_bit_cast(unsigned, f);
  u += 0x7fff + ((u >> 16) & 1);   // RNE
  return u >> 16;
}

// async global->LDS, 16B per lane. LDS dest must be waveuniform + lane*16.
__device__ __forceinline__ void async_copy16(const void* gptr, void* lptr) {
  auto g = (const __attribute__((address_space(1))) unsigned int*)(unsigned long long)gptr;
  unsigned loff = (unsigned)(unsigned long long)lptr;  // low 32 bits == LDS offset
  auto l = (__attribute__((address_space(3))) unsigned int*)loff;
  __builtin_amdgcn_global_load_lds(g, l, 16, 0, 0);
}

__global__ void convert_f32_bf16(const float* __restrict__ src,
                                 unsigned short* __restrict__ dst, int n4) {
  int i = blockIdx.x * blockDim.x + threadIdx.x;
  if (i >= n4) return;
  float4 f = ((const float4*)src)[i];
  ushort4 o;
  o.x = (unsigned short)f2bf(f.x);
  o.y = (unsigned short)f2bf(f.y);
  o.z = (unsigned short)f2bf(f.z);
  o.w = (unsigned short)f2bf(f.w);
  ((ushort4*)dst)[i] = o;
}

// C[m,n] = mish(sum_k A[m,k]*W1[n,k] + b1[n]) -> bf16 h
__global__ __launch_bounds__(256) void gemm1_mish(
    const float* __restrict__ A, const unsigned short* __restrict__ B,
    const float* __restrict__ b1, const int* __restrict__ flat_idx,
    unsigned short* __restrict__ Hout) {
  __shared__ __align__(16) unsigned short As[128 * 64];
  __shared__ __align__(16) unsigned short Bs[128 * 64];
  __shared__ int rowmap[128];

  const int tid = threadIdx.x;
  const int lane = tid & 63;
  const int wave = tid >> 6;
  const int wm = wave >> 1, wn = wave & 1;
  const int m0 = blockIdx.y * 128;
  const int n0 = blockIdx.x * 128;

  if (tid < 128) rowmap[tid] = flat_idx[m0 + tid];
  __syncthreads();

  f32x4 acc[4][4];
#pragma unroll
  for (int i = 0; i < 4; i++)
#pragma unroll
    for (int j = 0; j < 4; j++) acc[i][j] = f32x4{0.f, 0.f, 0.f, 0.f};

  for (int kk = 0; kk < H_DIM; kk += 64) {
    // B tile: 128 rows x 64 cols bf16 via global_load_lds (xor-swizzled source)
#pragma unroll
    for (int it = 0; it < 4; ++it) {
      int id = it * 256 + tid;
      int row = id >> 3, c8 = id & 7;
      int gc8 = c8 ^ (row & 7);
      async_copy16(B + (size_t)(n0 + row) * H_DIM + kk + gc8 * 8, &Bs[id * 8]);
    }
    // A tile: fp32 load + cvt to bf16 through VGPRs
#pragma unroll
    for (int it = 0; it < 4; ++it) {
      int id = it * 256 + tid;
      int row = id >> 3, c8 = id & 7;
      int gc8 = c8 ^ (row & 7);
      const float* src = A + (size_t)rowmap[row] * H_DIM + kk + gc8 * 8;
      float4 fa = *(const float4*)src;
      float4 fb = *(const float4*)(src + 4);
      uint4 pk;
      pk.x = (f2bf(fa.y) << 16) | f2bf(fa.x);
      pk.y = (f2bf(fa.w) << 16) | f2bf(fa.z);
      pk.z = (f2bf(fb.y) << 16) | f2bf(fb.x);
      pk.w = (f2bf(fb.w) << 16) | f2bf(fb.z);
      *(uint4*)&As[id * 8] = pk;
    }
    __syncthreads();
#pragma unroll
    for (int ks = 0; ks < 2; ++ks) {
      bf16x8 af[4], bg[4];
#pragma unroll
      for (int mt = 0; mt < 4; ++mt) {
        int r = wm * 64 + mt * 16 + (lane & 15);
        int j = (lane >> 4) + ks * 4;
        af[mt] = *(const bf16x8*)&As[r * 64 + ((j ^ (r & 7)) << 3)];
      }
#pragma unroll
      for (int nt = 0; nt < 4; ++nt) {
        int r = wn * 64 + nt * 16 + (lane & 15);
        int j = (lane >> 4) + ks * 4;
        bg[nt] = *(const bf16x8*)&Bs[r * 64 + ((j ^ (r & 7)) << 3)];
      }
#pragma unroll
      for (int mt = 0; mt < 4; ++mt)
#pragma unroll
        for (int nt = 0; nt < 4; ++nt)
          acc[mt][nt] = __builtin_amdgcn_mfma_f32_16x16x32_bf16(
              af[mt], bg[nt], acc[mt][nt], 0, 0, 0);
    }
    __syncthreads();
  }

#pragma unroll
  for (int nt = 0; nt < 4; ++nt) {
    int gc = n0 + wn * 64 + nt * 16 + (lane & 15);
    float bias = b1[gc];
#pragma unroll
    for (int mt = 0; mt < 4; ++mt) {
#pragma unroll
      for (int r = 0; r < 4; ++r) {
        int grow = m0 + wm * 64 + mt * 16 + ((lane >> 4) << 2) + r;
        float x = acc[mt][nt][r] + bias;
        // mish(x) = x*tanh(softplus(x)) = x*u/(u+2), u = t(t+2), t = e^x
        float t = __expf(x);
        float u = t * (t + 2.f);
        float y = (x < 10.f) ? x * u * __builtin_amdgcn_rcpf(u + 2.f) : x;
        Hout[(size_t)grow * DMID + gc] = (unsigned short)f2bf(y);
      }
    }
  }
}

// out[seg[m], n] += sum_k h[m,k]*W2[n,k] + b2[n]
__global__ __launch_bounds__(256) void gemm2_pool(
    const unsigned short* __restrict__ Hin, const unsigned short* __restrict__ W2b,
    const float* __restrict__ b2, const int* __restrict__ seg,
    float* __restrict__ out) {
  __shared__ __align__(16) unsigned short As[128 * 64];
  __shared__ __align__(16) unsigned short Bs[128 * 64];

  const int tid = threadIdx.x;
  const int lane = tid & 63;
  const int wave = tid >> 6;
  const int wm = wave >> 1, wn = wave & 1;
  const int m0 = blockIdx.y * 128;
  const int n0 = blockIdx.x * 128;

  f32x4 acc[4][4];
#pragma unroll
  for (int i = 0; i < 4; i++)
#pragma unroll
    for (int j = 0; j < 4; j++) acc[i][j] = f32x4{0.f, 0.f, 0.f, 0.f};

  for (int kk = 0; kk < DMID; kk += 64) {
#pragma unroll
    for (int it = 0; it < 4; ++it) {
      int id = it * 256 + tid;
      int row = id >> 3, c8 = id & 7;
      int gc8 = c8 ^ (row & 7);
      async_copy16(Hin + (size_t)(m0 + row) * DMID + kk + gc8 * 8, &As[id * 8]);
      async_copy16(W2b + (size_t)(n0 + row) * DMID + kk + gc8 * 8, &Bs[id * 8]);
    }
    __syncthreads();
#pragma unroll
    for (int ks = 0; ks < 2; ++ks) {
      bf16x8 af[4], bg[4];
#pragma unroll
      for (int mt = 0; mt < 4; ++mt) {
        int r = wm * 64 + mt * 16 + (lane & 15);
        int j = (lane >> 4) + ks * 4;
        af[mt] = *(const bf16x8*)&As[r * 64 + ((j ^ (r & 7)) << 3)];
      }
#pragma unroll
      for (int nt = 0; nt < 4; ++nt) {
        int r = wn * 64 + nt * 16 + (lane & 15);
        int j = (lane >> 4) + ks * 4;
        bg[nt] = *(const bf16x8*)&Bs[r * 64 + ((j ^ (r & 7)) << 3)];
      }
#pragma unroll
      for (int mt = 0; mt < 4; ++mt)
#pragma unroll
        for (int nt = 0; nt < 4; ++nt)
          acc[mt][nt] = __builtin_amdgcn_mfma_f32_16x16x32_bf16(
              af[mt], bg[nt], acc[mt][nt], 0, 0, 0);
    }
    __syncthreads();
  }

  int s0 = seg[m0];
  int s1 = seg[m0 + 127];
  if (s0 == s1) {  // whole block in one segment (sorted ids): wave-level reduce
    float* o = out + s0 * DOUT;
#pragma unroll
    for (int nt = 0; nt < 4; ++nt) {
      int gc = n0 + wn * 64 + nt * 16 + (lane & 15);
      float s = 16.f * b2[gc];
#pragma unroll
      for (int mt = 0; mt < 4; ++mt)
#pragma unroll
        for (int r = 0; r < 4; ++r) s += acc[mt][nt][r];
      s += __shfl_xor(s, 16);
      s += __shfl_xor(s, 32);
      if ((lane >> 4) == 0) atomicAdd(&o[gc], s);
    }
  } else {  // boundary block (rare): per-element atomics
#pragma unroll
    for (int nt = 0; nt < 4; ++nt) {
      int gc = n0 + wn * 64 + nt * 16 + (lane & 15);
      float bias = b2[gc];
#pragma unroll
      for (int mt = 0; mt < 4; ++mt) {
#pragma unroll
        for (int r = 0; r < 4; ++r) {
          int token = m0 + wm * 64 + mt * 16 + ((lane >> 4) << 2) + r;
          atomicAdd(&out[seg[token] * DOUT + gc], acc[mt][nt][r] + bias);
        }
      }
    }
  }
}

extern "C" void kernel_launch(void* const* d_in, const int* in_sizes, int n_in,
                              void* d_out, int out_size, void* d_ws, size_t ws_size,
                              hipStream_t stream) {
  const float* hidden = (const float*)d_in[0];
  const float* W1 = (const float*)d_in[1];
  const float* b1 = (const float*)d_in[2];
  const float* W2 = (const float*)d_in[3];
  const float* b2 = (const float*)d_in[4];
  const int* flat_idx = (const int*)d_in[5];
  const int* seg = (const int*)d_in[6];
  float* out = (float*)d_out;

  unsigned short* W1b = (unsigned short*)d_ws;       // 1024*2048*2 = 4 MiB
  unsigned short* W2b = W1b + (size_t)DMID * H_DIM;  // 256*1024*2  = 512 KiB
  unsigned short* Hbuf = W2b + (size_t)DOUT * DMID;  // 32768*1024*2 = 64 MiB
  size_t need = ((size_t)DMID * H_DIM + (size_t)DOUT * DMID + (size_t)NTOK * DMID) * 2;
  if (ws_size < need) return;

  hipMemsetAsync(d_out, 0, (size_t)NIMG * DOUT * sizeof(float), stream);
  convert_f32_bf16<<<(DMID * H_DIM / 4 + 255) / 256, 256, 0, stream>>>(W1, W1b, DMID * H_DIM / 4);
  convert_f32_bf16<<<(DOUT * DMID / 4 + 255) / 256, 256, 0, stream>>>(W2, W2b, DOUT * DMID / 4);
  gemm1_mish<<<dim3(8, 256), 256, 0, stream>>>(hidden, W1b, b1, flat_idx, Hbuf);
  gemm2_pool<<<dim3(2, 256), 256, 0, stream>>>(Hbuf, W2b, b2, seg, out);
}

// Round 2
// 613.937 us; speedup vs baseline: 1.1054x; 1.1054x over previous
//
#include <hip/hip_runtime.h>

#define H_DIM 2048
#define DMID  1024
#define DOUT  256
#define NTOK  32768
#define NIMG  32

typedef __attribute__((ext_vector_type(8))) __bf16 bf16x8;
typedef __attribute__((ext_vector_type(4))) float f32x4;

__device__ __forceinline__ unsigned f2bf(float f) {
  unsigned u = __builtin_bit_cast(unsigned, f);
  u += 0x7fff + ((u >> 16) & 1);   // RNE
  return u >> 16;
}

// async global->LDS, 16B per lane. LDS dest must be wave-uniform base + lane*16.
__device__ __forceinline__ void async_copy16(const void* gptr, void* lptr) {
  auto g = (const __attribute__((address_space(1))) unsigned int*)(unsigned long long)gptr;
  unsigned loff = (unsigned)(unsigned long long)lptr;
  auto l = (__attribute__((address_space(3))) unsigned int*)loff;
  __builtin_amdgcn_global_load_lds(g, l, 16, 0, 0);
}

__global__ void convert_f32_bf16(const float* __restrict__ src,
                                 unsigned short* __restrict__ dst, int n4) {
  int i = blockIdx.x * blockDim.x + threadIdx.x;
  if (i >= n4) return;
  float4 f = ((const float4*)src)[i];
  ushort4 o;
  o.x = (unsigned short)f2bf(f.x);
  o.y = (unsigned short)f2bf(f.y);
  o.z = (unsigned short)f2bf(f.z);
  o.w = (unsigned short)f2bf(f.w);
  ((ushort4*)dst)[i] = o;
}

// One block per token row: gather via flat_idx + fp32->bf16. 8 elems/thread.
__global__ __launch_bounds__(256) void gather_convert_A(
    const float* __restrict__ hidden, const int* __restrict__ flat_idx,
    unsigned short* __restrict__ Abuf) {
  int row = blockIdx.x;
  int src_row = flat_idx[row];
  const float* src = hidden + (size_t)src_row * H_DIM + threadIdx.x * 8;
  float4 fa = *(const float4*)src;
  float4 fb = *(const float4*)(src + 4);
  uint4 pk;
  pk.x = (f2bf(fa.y) << 16) | f2bf(fa.x);
  pk.y = (f2bf(fa.w) << 16) | f2bf(fa.z);
  pk.z = (f2bf(fb.y) << 16) | f2bf(fb.x);
  pk.w = (f2bf(fb.w) << 16) | f2bf(fb.z);
  *(uint4*)(Abuf + (size_t)row * H_DIM + threadIdx.x * 8) = pk;
}

// C[m,n] = mish(sum_k A[m,k]*W1[n,k] + b1[n]) -> bf16 h
// PRE=true: A pre-gathered bf16 (full async path). PRE=false: fp32 + inline cvt.
template <bool PRE>
__global__ __launch_bounds__(256) void gemm1_mish(
    const float* __restrict__ A32, const unsigned short* __restrict__ Abf,
    const unsigned short* __restrict__ B, const float* __restrict__ b1,
    const int* __restrict__ flat_idx, unsigned short* __restrict__ Hout) {
  __shared__ __align__(16) unsigned short As[128 * 64];
  __shared__ __align__(16) unsigned short Bs[128 * 64];
  __shared__ int rowmap[128];

  const int tid = threadIdx.x;
  const int lane = tid & 63;
  const int wave = tid >> 6;
  const int wm = wave >> 1, wn = wave & 1;
  const int m0 = blockIdx.y * 128;
  const int n0 = blockIdx.x * 128;

  if constexpr (!PRE) {
    if (tid < 128) rowmap[tid] = flat_idx[m0 + tid];
    __syncthreads();
  }

  f32x4 acc[4][4];
#pragma unroll
  for (int i = 0; i < 4; i++)
#pragma unroll
    for (int j = 0; j < 4; j++) acc[i][j] = f32x4{0.f, 0.f, 0.f, 0.f};

  for (int kk = 0; kk < H_DIM; kk += 64) {
#pragma unroll
    for (int it = 0; it < 4; ++it) {
      int id = it * 256 + tid;
      int row = id >> 3, c8 = id & 7;
      int gc8 = c8 ^ (row & 7);
      async_copy16(B + (size_t)(n0 + row) * H_DIM + kk + gc8 * 8, &Bs[id * 8]);
    }
    if constexpr (PRE) {
#pragma unroll
      for (int it = 0; it < 4; ++it) {
        int id = it * 256 + tid;
        int row = id >> 3, c8 = id & 7;
        int gc8 = c8 ^ (row & 7);
        async_copy16(Abf + (size_t)(m0 + row) * H_DIM + kk + gc8 * 8, &As[id * 8]);
      }
    } else {
#pragma unroll
      for (int it = 0; it < 4; ++it) {
        int id = it * 256 + tid;
        int row = id >> 3, c8 = id & 7;
        int gc8 = c8 ^ (row & 7);
        const float* src = A32 + (size_t)rowmap[row] * H_DIM + kk + gc8 * 8;
        float4 fa = *(const float4*)src;
        float4 fb = *(const float4*)(src + 4);
        uint4 pk;
        pk.x = (f2bf(fa.y) << 16) | f2bf(fa.x);
        pk.y = (f2bf(fa.w) << 16) | f2bf(fa.z);
        pk.z = (f2bf(fb.y) << 16) | f2bf(fb.x);
        pk.w = (f2bf(fb.w) << 16) | f2bf(fb.z);
        *(uint4*)&As[id * 8] = pk;
      }
    }
    __syncthreads();
#pragma unroll
    for (int ks = 0; ks < 2; ++ks) {
      bf16x8 af[4], bg[4];
#pragma unroll
      for (int mt = 0; mt < 4; ++mt) {
        int r = wm * 64 + mt * 16 + (lane & 15);
        int j = (lane >> 4) + ks * 4;
        af[mt] = *(const bf16x8*)&As[r * 64 + ((j ^ (r & 7)) << 3)];
      }
#pragma unroll
      for (int nt = 0; nt < 4; ++nt) {
        int r = wn * 64 + nt * 16 + (lane & 15);
        int j = (lane >> 4) + ks * 4;
        bg[nt] = *(const bf16x8*)&Bs[r * 64 + ((j ^ (r & 7)) << 3)];
      }
#pragma unroll
      for (int mt = 0; mt < 4; ++mt)
#pragma unroll
        for (int nt = 0; nt < 4; ++nt)
          acc[mt][nt] = __builtin_amdgcn_mfma_f32_16x16x32_bf16(
              af[mt], bg[nt], acc[mt][nt], 0, 0, 0);
    }
    __syncthreads();
  }

#pragma unroll
  for (int nt = 0; nt < 4; ++nt) {
    int gc = n0 + wn * 64 + nt * 16 + (lane & 15);
    float bias = b1[gc];
#pragma unroll
    for (int mt = 0; mt < 4; ++mt) {
#pragma unroll
      for (int r = 0; r < 4; ++r) {
        int grow = m0 + wm * 64 + mt * 16 + ((lane >> 4) << 2) + r;
        float x = acc[mt][nt][r] + bias;
        // mish(x) = x*tanh(softplus(x)) = x*u/(u+2), u = t(t+2), t = e^x
        float t = __expf(x);
        float u = t * (t + 2.f);
        float y = (x < 10.f) ? x * u * __builtin_amdgcn_rcpf(u + 2.f) : x;
        Hout[(size_t)grow * DMID + gc] = (unsigned short)f2bf(y);
      }
    }
  }
}

// out[seg[m], n] += sum_k h[m,k]*W2[n,k] + b2[n]
__global__ __launch_bounds__(256) void gemm2_pool(
    const unsigned short* __restrict__ Hin, const unsigned short* __restrict__ W2b,
    const float* __restrict__ b2, const int* __restrict__ seg,
    float* __restrict__ out) {
  __shared__ __align__(16) unsigned short As[128 * 64];
  __shared__ __align__(16) unsigned short Bs[128 * 64];
  __shared__ int segl[128];

  const int tid = threadIdx.x;
  const int lane = tid & 63;
  const int wave = tid >> 6;
  const int wm = wave >> 1, wn = wave & 1;
  const int m0 = blockIdx.y * 128;
  const int n0 = blockIdx.x * 128;

  if (tid < 128) segl[tid] = seg[m0 + tid];
  __syncthreads();

  f32x4 acc[4][4];
#pragma unroll
  for (int i = 0; i < 4; i++)
#pragma unroll
    for (int j = 0; j < 4; j++) acc[i][j] = f32x4{0.f, 0.f, 0.f, 0.f};

  for (int kk = 0; kk < DMID; kk += 64) {
#pragma unroll
    for (int it = 0; it < 4; ++it) {
      int id = it * 256 + tid;
      int row = id >> 3, c8 = id & 7;
      int gc8 = c8 ^ (row & 7);
      async_copy16(Hin + (size_t)(m0 + row) * DMID + kk + gc8 * 8, &As[id * 8]);
      async_copy16(W2b + (size_t)(n0 + row) * DMID + kk + gc8 * 8, &Bs[id * 8]);
    }
    __syncthreads();
#pragma unroll
    for (int ks = 0; ks < 2; ++ks) {
      bf16x8 af[4], bg[4];
#pragma unroll
      for (int mt = 0; mt < 4; ++mt) {
        int r = wm * 64 + mt * 16 + (lane & 15);
        int j = (lane >> 4) + ks * 4;
        af[mt] = *(const bf16x8*)&As[r * 64 + ((j ^ (r & 7)) << 3)];
      }
#pragma unroll
      for (int nt = 0; nt < 4; ++nt) {
        int r = wn * 64 + nt * 16 + (lane & 15);
        int j = (lane >> 4) + ks * 4;
        bg[nt] = *(const bf16x8*)&Bs[r * 64 + ((j ^ (r & 7)) << 3)];
      }
#pragma unroll
      for (int mt = 0; mt < 4; ++mt)
#pragma unroll
        for (int nt = 0; nt < 4; ++nt)
          acc[mt][nt] = __builtin_amdgcn_mfma_f32_16x16x32_bf16(
              af[mt], bg[nt], acc[mt][nt], 0, 0, 0);
    }
    __syncthreads();
  }

  int s0 = segl[0];
  int s1 = segl[127];
  if (s0 == s1) {  // whole block in one segment: wave-level reduce, 1 atomic/col/wave
    float* o = out + s0 * DOUT;
#pragma unroll
    for (int nt = 0; nt < 4; ++nt) {
      int gc = n0 + wn * 64 + nt * 16 + (lane & 15);
      float s = 16.f * b2[gc];
#pragma unroll
      for (int mt = 0; mt < 4; ++mt)
#pragma unroll
        for (int r = 0; r < 4; ++r) s += acc[mt][nt][r];
      s += __shfl_xor(s, 16);
      s += __shfl_xor(s, 32);
      if ((lane >> 4) == 0) atomicAdd(&o[gc], s);
    }
  } else {  // boundary block: masked reduce per segment present (sorted ids)
    int myseg[16];
#pragma unroll
    for (int mt = 0; mt < 4; ++mt)
#pragma unroll
      for (int r = 0; r < 4; ++r)
        myseg[mt * 4 + r] = segl[wm * 64 + mt * 16 + ((lane >> 4) << 2) + r];
    for (int s = s0; s <= s1; ++s) {
#pragma unroll
      for (int nt = 0; nt < 4; ++nt) {
        int gc = n0 + wn * 64 + nt * 16 + (lane & 15);
        float bias = b2[gc];
        float v = 0.f;
#pragma unroll
        for (int mt = 0; mt < 4; ++mt)
#pragma unroll
          for (int r = 0; r < 4; ++r)
            v += (myseg[mt * 4 + r] == s) ? (acc[mt][nt][r] + bias) : 0.f;
        v += __shfl_xor(v, 16);
        v += __shfl_xor(v, 32);
        if ((lane >> 4) == 0) atomicAdd(&out[s * DOUT + gc], v);
      }
    }
  }
}

extern "C" void kernel_launch(void* const* d_in, const int* in_sizes, int n_in,
                              void* d_out, int out_size, void* d_ws, size_t ws_size,
                              hipStream_t stream) {
  const float* hidden = (const float*)d_in[0];
  const float* W1 = (const float*)d_in[1];
  const float* b1 = (const float*)d_in[2];
  const float* W2 = (const float*)d_in[3];
  const float* b2 = (const float*)d_in[4];
  const int* flat_idx = (const int*)d_in[5];
  const int* seg = (const int*)d_in[6];
  float* out = (float*)d_out;

  unsigned short* W1b = (unsigned short*)d_ws;       // 1024*2048*2 = 4 MiB
  unsigned short* W2b = W1b + (size_t)DMID * H_DIM;  // 256*1024*2  = 512 KiB
  unsigned short* Hbuf = W2b + (size_t)DOUT * DMID;  // 32768*1024*2 = 64 MiB
  unsigned short* Abuf = Hbuf + (size_t)NTOK * DMID; // 32768*2048*2 = 128 MiB

  size_t need_slow = ((size_t)DMID * H_DIM + (size_t)DOUT * DMID + (size_t)NTOK * DMID) * 2;
  size_t need_fast = need_slow + (size_t)NTOK * H_DIM * 2;
  if (ws_size < need_slow) return;
  bool fast = ws_size >= need_fast;

  hipMemsetAsync(d_out, 0, (size_t)NIMG * DOUT * sizeof(float), stream);
  convert_f32_bf16<<<(DMID * H_DIM / 4 + 255) / 256, 256, 0, stream>>>(W1, W1b, DMID * H_DIM / 4);
  convert_f32_bf16<<<(DOUT * DMID / 4 + 255) / 256, 256, 0, stream>>>(W2, W2b, DOUT * DMID / 4);
  if (fast) {
    gather_convert_A<<<NTOK, 256, 0, stream>>>(hidden, flat_idx, Abuf);
    gemm1_mish<true><<<dim3(8, 256), 256, 0, stream>>>(nullptr, Abuf, W1b, b1, nullptr, Hbuf);
  } else {
    gemm1_mish<false><<<dim3(8, 256), 256, 0, stream>>>(hidden, nullptr, W1b, b1, flat_idx, Hbuf);
  }
  gemm2_pool<<<dim3(2, 256), 256, 0, stream>>>(Hbuf, W2b, b2, seg, out);
}